// Round 8
// baseline (578.006 us; speedup 1.0000x reference)
//
#include <hip/hip_runtime.h>
#include <hip/hip_fp16.h>

#define N_ENTITY 64368
#define N_REL 40
#define DIM 128
#define N_BASES 8
#define N_EDGES 500000
#define BATCH 64
#define SEED_LEN 32
#define NROWS (BATCH * SEED_LEN)            // 2048
#define SCAN_NB ((N_ENTITY + 255) / 256)    // 252
#define NPAD (SCAN_NB * 256)                // 64512 (block-aligned entity count)

#define CAP_S 40                             // src-bucket capacity (Poisson(7.8))
#define CAP_D 40                             // dst-bucket (msg rows per dst)
#define OVF_CAP 4096                         // dst-overflow rows (never hit)

struct alignas(8)  half4 { __half2 lo, hi; };
struct alignas(16) h8    { __half2 a, b, c, d; };

// ===========================================================================
// K1 scatter: one pass over edges.
//   kd = atomicAdd(cntd[dst]):
//     kd < CAP_D  -> msg row = dst*CAP_D + kd
//     else        -> msg row = N_ENTITY*CAP_D + o,  ovfd[o] = dst  (p ~ 0)
//   pack = row<<6 | type  (row < 2^22)
//   ks = atomicAdd(cnts[src]) -> slots[src*CAP_S + ks] = pack
//   src overflow (p ~ 1e-16): compute the msg row HERE, scalar.
// ===========================================================================
__global__ __launch_bounds__(256) void k_scatter(
    const int* __restrict__ esrc, const int* __restrict__ edst,
    const int* __restrict__ etype, const float* __restrict__ basis,
    const float* __restrict__ att, int* __restrict__ cnts,
    int* __restrict__ cntd, int* __restrict__ novf, int* __restrict__ ovfd,
    int* __restrict__ slots, __half* __restrict__ msg)
{
    int e = blockIdx.x * 256 + threadIdx.x;
    if (e >= N_EDGES) return;
    int s = esrc[e], d = edst[e], t = etype[e];

    int kd = atomicAdd(&cntd[d], 1);
    int row;
    if (kd < CAP_D) {
        row = d * CAP_D + kd;
    } else {                                  // statistically impossible
        int o = atomicAdd(novf, 1);
        if (o >= OVF_CAP) o = OVF_CAP - 1;    // clamp (cannot happen)
        ovfd[o] = d;
        row = N_ENTITY * CAP_D + o;
    }
    int pack = (row << 6) | t;

    int ks = atomicAdd(&cnts[s], 1);
    if (ks < CAP_S) {
        slots[(size_t)s * CAP_S + ks] = pack;
    } else {
        // statistically impossible; scalar correctness path
        const size_t bstride = (size_t)N_ENTITY * DIM;
        for (int dd = 0; dd < DIM; ++dd) {
            float m = 0.f;
            #pragma unroll
            for (int b = 0; b < N_BASES; ++b)
                m += att[t * N_BASES + b] * basis[b * bstride + (size_t)s * DIM + dd];
            msg[(size_t)row * DIM + dd] = __float2half(m);
        }
    }
}

// ===========================================================================
// K2 phaseA: one HALF-WAVE per src. Loads the 8 basis rows once (streaming
// 4KB/src), then per outgoing edge computes m = sum_b c_b*row_b and writes
// the fp16 msg row at its assigned position. Branch-free, 4 edges in flight.
// ===========================================================================
#define MSG_ROW(pp, mm)                                                      \
    {                                                                        \
        const float* cp = att_s + ((pp) & 63) * N_BASES;                     \
        float4 c0 = *(const float4*)(cp);                                    \
        float4 c1 = *(const float4*)(cp + 4);                                \
        mm.x = c0.x*r0.x + c0.y*r1.x + c0.z*r2.x + c0.w*r3.x                 \
             + c1.x*r4.x + c1.y*r5.x + c1.z*r6.x + c1.w*r7.x;                \
        mm.y = c0.x*r0.y + c0.y*r1.y + c0.z*r2.y + c0.w*r3.y                 \
             + c1.x*r4.y + c1.y*r5.y + c1.z*r6.y + c1.w*r7.y;                \
        mm.z = c0.x*r0.z + c0.y*r1.z + c0.z*r2.z + c0.w*r3.z                 \
             + c1.x*r4.z + c1.y*r5.z + c1.z*r6.z + c1.w*r7.z;                \
        mm.w = c0.x*r0.w + c0.y*r1.w + c0.z*r2.w + c0.w*r3.w                 \
             + c1.x*r4.w + c1.y*r5.w + c1.z*r6.w + c1.w*r7.w;                \
    }

#define MSG_STORE(pp, mm)                                                    \
    {                                                                        \
        half4 h;                                                             \
        h.lo = __floats2half2_rn(mm.x, mm.y);                                \
        h.hi = __floats2half2_rn(mm.z, mm.w);                                \
        *(half4*)(msg + ((size_t)((pp) >> 6) << 7) + (l32 << 2)) = h;        \
    }

__global__ __launch_bounds__(256) void k_phaseA(
    const int* __restrict__ cnts, const int* __restrict__ slots,
    const float* __restrict__ basis, const float* __restrict__ att,
    __half* __restrict__ msg)
{
    __shared__ float att_s[N_REL * N_BASES];
    int tid = threadIdx.x;
    for (int i = tid; i < N_REL * N_BASES; i += 256) att_s[i] = att[i];
    __syncthreads();

    int sid = (blockIdx.x * 256 + tid) >> 5;      // half-wave id == src id
    int l32 = tid & 31;
    if (sid >= N_ENTITY) return;
    int cnt = cnts[sid];
    if (cnt == 0) return;
    if (cnt > CAP_S) cnt = CAP_S;                 // overflow handled in scatter
    const int* sl = slots + (size_t)sid * CAP_S;

    const size_t bstride = (size_t)N_ENTITY * DIM;
    const float* bp = basis + (size_t)sid * DIM + l32 * 4;
    float4 r0 = *(const float4*)(bp + 0 * bstride);
    float4 r1 = *(const float4*)(bp + 1 * bstride);
    float4 r2 = *(const float4*)(bp + 2 * bstride);
    float4 r3 = *(const float4*)(bp + 3 * bstride);
    float4 r4 = *(const float4*)(bp + 4 * bstride);
    float4 r5 = *(const float4*)(bp + 5 * bstride);
    float4 r6 = *(const float4*)(bp + 6 * bstride);
    float4 r7 = *(const float4*)(bp + 7 * bstride);

    int j = 0;
    for (; j + 3 < cnt; j += 4) {                 // 4 edges in flight
        int p0 = sl[j], p1 = sl[j + 1], p2 = sl[j + 2], p3 = sl[j + 3];
        float4 m0, m1, m2, m3;
        MSG_ROW(p0, m0) MSG_ROW(p1, m1) MSG_ROW(p2, m2) MSG_ROW(p3, m3)
        MSG_STORE(p0, m0) MSG_STORE(p1, m1) MSG_STORE(p2, m2) MSG_STORE(p3, m3)
    }
    for (; j < cnt; ++j) {
        int p0 = sl[j];
        float4 m0;
        MSG_ROW(p0, m0)
        MSG_STORE(p0, m0)
    }
}

// ===========================================================================
// K3 phaseB: one wave per dst; 16 lanes x 16B cover one 256B msg row, the
// wave reduces 4 rows per iteration (h8 loads); cross-row combine via two
// shfl_xor; fused mean + root + bias. Overflow rows scanned only if novf>0.
// ===========================================================================
__global__ __launch_bounds__(256) void k_phaseB(
    const int* __restrict__ cntd, const int* __restrict__ novf,
    const int* __restrict__ ovfd, const __half* __restrict__ msg,
    const float* __restrict__ root, const float* __restrict__ bias,
    float* __restrict__ agg)
{
    int wid  = (int)((blockIdx.x * 256 + threadIdx.x) >> 6);
    int lane = threadIdx.x & 63;
    if (wid >= N_ENTITY) return;
    int g = lane >> 4;                            // row group 0..3
    int q = lane & 15;                            // 16B chunk within row

    int c = cntd[wid];
    int n = (c < CAP_D) ? c : CAP_D;
    const __half* base = msg + (size_t)wid * (CAP_D * DIM) + (q << 3);

    float a0 = 0.f, a1 = 0.f, a2 = 0.f, a3 = 0.f;
    float a4 = 0.f, a5 = 0.f, a6 = 0.f, a7 = 0.f;
    for (int j = 0; j < n; j += 4) {
        int r = j + g;
        h8 v = *(const h8*)(base + ((size_t)r << 7));   // r < CAP_D: in bounds
        bool ok = (r < n);
        float2 f0 = __half22float2(v.a);
        float2 f1 = __half22float2(v.b);
        float2 f2 = __half22float2(v.c);
        float2 f3 = __half22float2(v.d);
        if (ok) {
            a0 += f0.x; a1 += f0.y; a2 += f1.x; a3 += f1.y;
            a4 += f2.x; a5 += f2.y; a6 += f3.x; a7 += f3.y;
        }
    }

    int nov = *novf;                              // normally 0: one scalar load
    if (nov > 0) {
        if (nov > OVF_CAP) nov = OVF_CAP;
        for (int k = 0; k < nov; ++k) {
            if (ovfd[k] == wid && g == 0) {       // add once (group 0 only)
                const __half* p = msg + ((size_t)(N_ENTITY * CAP_D) + k) * DIM
                                + (q << 3);
                h8 v = *(const h8*)p;
                float2 f0 = __half22float2(v.a);
                float2 f1 = __half22float2(v.b);
                float2 f2 = __half22float2(v.c);
                float2 f3 = __half22float2(v.d);
                a0 += f0.x; a1 += f0.y; a2 += f1.x; a3 += f1.y;
                a4 += f2.x; a5 += f2.y; a6 += f3.x; a7 += f3.y;
            }
        }
    }

    // reduce across the 4 row groups (lanes l, l^16, l^32, l^48)
    a0 += __shfl_xor(a0, 16, 64); a0 += __shfl_xor(a0, 32, 64);
    a1 += __shfl_xor(a1, 16, 64); a1 += __shfl_xor(a1, 32, 64);
    a2 += __shfl_xor(a2, 16, 64); a2 += __shfl_xor(a2, 32, 64);
    a3 += __shfl_xor(a3, 16, 64); a3 += __shfl_xor(a3, 32, 64);
    a4 += __shfl_xor(a4, 16, 64); a4 += __shfl_xor(a4, 32, 64);
    a5 += __shfl_xor(a5, 16, 64); a5 += __shfl_xor(a5, 32, 64);
    a6 += __shfl_xor(a6, 16, 64); a6 += __shfl_xor(a6, 32, 64);
    a7 += __shfl_xor(a7, 16, 64); a7 += __shfl_xor(a7, 32, 64);

    // lane (g,q) writes dims q*8 + g*2, +1  (static register selection)
    float vx, vy;
    if      (g == 0) { vx = a0; vy = a1; }
    else if (g == 1) { vx = a2; vy = a3; }
    else if (g == 2) { vx = a4; vy = a5; }
    else             { vx = a6; vy = a7; }

    float inv = 1.0f / fmaxf((float)c, 1.0f);
    int dof = (q << 3) + (g << 1);
    int o = wid * DIM + dof;
    float2 r  = *(const float2*)(root + o);
    float2 bb = *(const float2*)(bias + dof);
    float2 outv;
    outv.x = vx * inv + r.x + bb.x;
    outv.y = vy * inv + r.y + bb.y;
    *(float2*)(agg + o) = outv;
}

// ===========================================================================
// Fused attention: T = tanh(H@A) in registers, e = T@b, softmax, u.
// ===========================================================================
__global__ __launch_bounds__(256) void k_attn(
    const int* __restrict__ seed_ids, const float* __restrict__ nodes,
    const float* __restrict__ A, const float* __restrict__ Bv,
    float* __restrict__ uT)
{
    __shared__ float Hs[SEED_LEN * DIM];   // 16 KB
    __shared__ float ew[SEED_LEN];
    __shared__ float attw[SEED_LEN];

    int b = blockIdx.x, tid = threadIdx.x;

    for (int i = tid; i < SEED_LEN * DIM; i += 256) {
        int ss = i >> 7, d = i & 127;
        Hs[i] = nodes[(size_t)seed_ids[b * SEED_LEN + ss] * DIM + d];
    }
    __syncthreads();

    int jx = tid & 31;
    int iy = tid >> 5;
    float acc[4][4] = {{0,0,0,0},{0,0,0,0},{0,0,0,0},{0,0,0,0}};

    for (int d = 0; d < DIM; ++d) {
        const float4 a4 = *(const float4*)(A + d * DIM + jx * 4);
        float h0 = Hs[(iy * 4 + 0) * DIM + d];
        float h1 = Hs[(iy * 4 + 1) * DIM + d];
        float h2 = Hs[(iy * 4 + 2) * DIM + d];
        float h3 = Hs[(iy * 4 + 3) * DIM + d];
        acc[0][0] += h0 * a4.x; acc[0][1] += h0 * a4.y;
        acc[0][2] += h0 * a4.z; acc[0][3] += h0 * a4.w;
        acc[1][0] += h1 * a4.x; acc[1][1] += h1 * a4.y;
        acc[1][2] += h1 * a4.z; acc[1][3] += h1 * a4.w;
        acc[2][0] += h2 * a4.x; acc[2][1] += h2 * a4.y;
        acc[2][2] += h2 * a4.z; acc[2][3] += h2 * a4.w;
        acc[3][0] += h3 * a4.x; acc[3][1] += h3 * a4.y;
        acc[3][2] += h3 * a4.z; acc[3][3] += h3 * a4.w;
    }

    const float4 bv = *(const float4*)(Bv + jx * 4);
    #pragma unroll
    for (int i = 0; i < 4; ++i) {
        float pe = tanhf(acc[i][0]) * bv.x + tanhf(acc[i][1]) * bv.y
                 + tanhf(acc[i][2]) * bv.z + tanhf(acc[i][3]) * bv.w;
        pe += __shfl_xor(pe, 1, 64);
        pe += __shfl_xor(pe, 2, 64);
        pe += __shfl_xor(pe, 4, 64);
        pe += __shfl_xor(pe, 8, 64);
        pe += __shfl_xor(pe, 16, 64);
        if (jx == 0) ew[iy * 4 + i] = pe;
    }
    __syncthreads();

    if (tid == 0) {
        float mx = -1e30f;
        for (int k = 0; k < SEED_LEN; ++k) mx = fmaxf(mx, ew[k]);
        float ssum = 0.0f;
        for (int k = 0; k < SEED_LEN; ++k) {
            float v = expf(ew[k] - mx);
            attw[k] = v; ssum += v;
        }
        float inv = 1.0f / ssum;
        for (int k = 0; k < SEED_LEN; ++k) attw[k] *= inv;
    }
    __syncthreads();

    if (tid < DIM) {
        float a = 0.0f;
        for (int k = 0; k < SEED_LEN; ++k) a += attw[k] * Hs[k * DIM + tid];
        uT[tid * BATCH + b] = a;
    }
}

// ===========================================================================
// Scores: out[b][n] = u[b]·nodes[n] + out_bias[n]
// ===========================================================================
__global__ __launch_bounds__(256) void k_scores(
    const float* __restrict__ nodes, const float* __restrict__ uT,
    const float* __restrict__ out_bias, float* __restrict__ out)
{
    __shared__ float Nl[DIM * 65];

    int tid = threadIdx.x;
    int n0  = blockIdx.x * 64;

    for (int i = tid; i < 64 * DIM; i += 256) {
        int n = i >> 7, d = i & 127;
        int gn = n0 + n;
        Nl[d * 65 + n] = (gn < N_ENTITY) ? nodes[(size_t)gn * DIM + d] : 0.0f;
    }
    __syncthreads();

    int w    = __builtin_amdgcn_readfirstlane(tid >> 6);
    int lane = tid & 63;
    int b0   = w * 16;

    float acc[16];
    #pragma unroll
    for (int k = 0; k < 16; ++k) acc[k] = 0.0f;

    #pragma unroll 4
    for (int d = 0; d < DIM; ++d) {
        float nv = Nl[d * 65 + lane];
        const float* up = uT + d * BATCH + b0;
        #pragma unroll
        for (int k = 0; k < 16; ++k) acc[k] += up[k] * nv;
    }

    int gn = n0 + lane;
    if (gn < N_ENTITY) {
        float ob = out_bias[gn];
        #pragma unroll
        for (int k = 0; k < 16; ++k)
            out[(size_t)(b0 + k) * N_ENTITY + gn] = acc[k] + ob;
    }
}

// ===========================================================================
// FALLBACK PATH (tiny ws): dst counting sort + fp32 gather.
// ===========================================================================
__global__ __launch_bounds__(256) void k_histF(
    const int* __restrict__ edst, int* __restrict__ hist)
{
    int e = blockIdx.x * 256 + threadIdx.x;
    if (e < N_EDGES) atomicAdd(&hist[edst[e]], 1);
}

__global__ __launch_bounds__(256) void k_scan1F(
    const int* __restrict__ hist, int* __restrict__ ptr,
    int* __restrict__ partial)
{
    __shared__ int s[256];
    int tid = threadIdx.x;
    int gid = blockIdx.x * 256 + tid;
    int v = hist[gid];
    s[tid] = v;
    __syncthreads();
    for (int off = 1; off < 256; off <<= 1) {
        int t = (tid >= off) ? s[tid - off] : 0;
        __syncthreads();
        s[tid] += t;
        __syncthreads();
    }
    ptr[gid] = s[tid] - v;
    if (tid == 255) partial[blockIdx.x] = s[255];
}

__global__ __launch_bounds__(256) void k_scan23F(
    int* __restrict__ ptr, const int* __restrict__ partial,
    int* __restrict__ work)
{
    __shared__ int s[256];
    int tid = threadIdx.x;
    int c   = blockIdx.x;
    int sum = 0;
    for (int k = tid; k < c; k += 256) sum += partial[k];
    s[tid] = sum;
    __syncthreads();
    for (int off = 128; off > 0; off >>= 1) {
        if (tid < off) s[tid] += s[tid + off];
        __syncthreads();
    }
    int p = ptr[c * 256 + tid] + s[0];
    ptr[c * 256 + tid]  = p;
    work[c * 256 + tid] = p;
}

__global__ __launch_bounds__(256) void k_scatterF(
    const int* __restrict__ esrc, const int* __restrict__ edst,
    const int* __restrict__ etype, int* __restrict__ work,
    int* __restrict__ meta)
{
    int e = blockIdx.x * 256 + threadIdx.x;
    if (e < N_EDGES) {
        int pos = atomicAdd(&work[edst[e]], 1);
        meta[pos] = esrc[e] * 64 + etype[e];
    }
}

#define ACC8(C0, C1, V0, V1, V2, V3, V4, V5, V6, V7)                         \
    acc.x += C0.x*V0.x + C0.y*V1.x + C0.z*V2.x + C0.w*V3.x                   \
           + C1.x*V4.x + C1.y*V5.x + C1.z*V6.x + C1.w*V7.x;                  \
    acc.y += C0.x*V0.y + C0.y*V1.y + C0.z*V2.y + C0.w*V3.y                   \
           + C1.x*V4.y + C1.y*V5.y + C1.z*V6.y + C1.w*V7.y;                  \
    acc.z += C0.x*V0.z + C0.y*V1.z + C0.z*V2.z + C0.w*V3.z                   \
           + C1.x*V4.z + C1.y*V5.z + C1.z*V6.z + C1.w*V7.z;                  \
    acc.w += C0.x*V0.w + C0.y*V1.w + C0.z*V2.w + C0.w*V3.w                   \
           + C1.x*V4.w + C1.y*V5.w + C1.z*V6.w + C1.w*V7.w;

__global__ __launch_bounds__(256) void k_gatherF(
    const int* __restrict__ ptr, const int* __restrict__ hist,
    const int* __restrict__ meta, const float* __restrict__ basis,
    const float* __restrict__ att, const float* __restrict__ root,
    const float* __restrict__ bias, float* __restrict__ agg)
{
    __shared__ float att_s[N_REL * N_BASES];
    int tid = threadIdx.x;
    for (int i = tid; i < N_REL * N_BASES; i += 256) att_s[i] = att[i];
    __syncthreads();

    int wid  = (int)((blockIdx.x * 256 + tid) >> 6);
    int lane = tid & 63;
    if (wid >= N_ENTITY) return;

    int half = lane >> 5;
    int l32  = lane & 31;
    int p   = ptr[wid];
    int cnt = hist[wid];
    const size_t bstride = (size_t)N_ENTITY * DIM;

    float4 acc = {0.f, 0.f, 0.f, 0.f};
    int j = 0;
    for (; j < cnt; j += 2) {
        int m0 = meta[p + j];
        bool has1 = (j + 1 < cnt);
        int m1 = has1 ? meta[p + j + 1] : m0;
        int m = half ? m1 : m0;
        float sc = (half && !has1) ? 0.0f : 1.0f;
        const float* bA = basis + (size_t)(m >> 6) * DIM + l32 * 4;
        float4 a0 = *(const float4*)(bA + 0 * bstride);
        float4 a1 = *(const float4*)(bA + 1 * bstride);
        float4 a2 = *(const float4*)(bA + 2 * bstride);
        float4 a3 = *(const float4*)(bA + 3 * bstride);
        float4 a4 = *(const float4*)(bA + 4 * bstride);
        float4 a5 = *(const float4*)(bA + 5 * bstride);
        float4 a6 = *(const float4*)(bA + 6 * bstride);
        float4 a7 = *(const float4*)(bA + 7 * bstride);
        float4 c0 = *(const float4*)(att_s + (m & 63) * N_BASES);
        float4 c1 = *(const float4*)(att_s + (m & 63) * N_BASES + 4);
        c0.x *= sc; c0.y *= sc; c0.z *= sc; c0.w *= sc;
        c1.x *= sc; c1.y *= sc; c1.z *= sc; c1.w *= sc;
        ACC8(c0, c1, a0, a1, a2, a3, a4, a5, a6, a7)
    }

    acc.x += __shfl_xor(acc.x, 32, 64);
    acc.y += __shfl_xor(acc.y, 32, 64);
    acc.z += __shfl_xor(acc.z, 32, 64);
    acc.w += __shfl_xor(acc.w, 32, 64);

    if (half == 0) {
        float inv = 1.0f / fmaxf((float)cnt, 1.0f);
        int o = wid * DIM + l32 * 4;
        float4 r  = *(const float4*)(root + o);
        float4 bb = *(const float4*)(bias + l32 * 4);
        float4 outv;
        outv.x = acc.x * inv + r.x + bb.x;
        outv.y = acc.y * inv + r.y + bb.y;
        outv.z = acc.z * inv + r.z + bb.z;
        outv.w = acc.w * inv + r.w + bb.w;
        *(float4*)(agg + o) = outv;
    }
}

// ===========================================================================
extern "C" void kernel_launch(void* const* d_in, const int* in_sizes, int n_in,
                              void* d_out, int out_size, void* d_ws, size_t ws_size,
                              hipStream_t stream)
{
    const int*   seed_ids  = (const int*)d_in[0];
    const int*   esrc      = (const int*)d_in[1];
    const int*   edst      = (const int*)d_in[2];
    const int*   etype     = (const int*)d_in[3];
    const float* basis     = (const float*)d_in[4];
    const float* att       = (const float*)d_in[5];
    const float* root      = (const float*)d_in[6];
    const float* rgcn_bias = (const float*)d_in[7];
    const float* attn_a    = (const float*)d_in[8];
    const float* attn_b    = (const float*)d_in[9];
    const float* out_bias  = (const float*)d_in[10];
    float* out = (float*)d_out;

    const size_t AGG_F   = (size_t)N_ENTITY * DIM;             // 8,239,104 words
    const size_t SLOTS_W = (size_t)N_ENTITY * CAP_S;           // 2,574,720 words
    const size_t MSG_W   = ((size_t)N_ENTITY * CAP_D + OVF_CAP) * DIM / 2;

    const size_t main_words = AGG_F + 2 * NPAD + 16 + OVF_CAP + SLOTS_W
                            + MSG_W + 2 * BATCH * DIM + 64;
    bool big = ws_size >= main_words * 4;

    if (big) {
        float*  agg   = (float*)d_ws;
        int*    cntd  = (int*)(agg + AGG_F);      // NPAD
        int*    cnts  = cntd + NPAD;              // NPAD
        int*    novf  = cnts + NPAD;              // 16
        int*    ovfd  = novf + 16;                // OVF_CAP
        int*    slots = ovfd + OVF_CAP;           // SLOTS_W
        __half* msg   = (__half*)(slots + SLOTS_W);
        float*  uT    = (float*)((int*)msg + MSG_W);

        // zero ONLY the counters (0.5 MB)
        hipMemsetAsync(cntd, 0, (2 * NPAD + 16) * sizeof(int), stream);

        k_scatter<<<(N_EDGES + 255) / 256, 256, 0, stream>>>(
            esrc, edst, etype, basis, att, cnts, cntd, novf, ovfd, slots, msg);
        k_phaseA<<<N_ENTITY / 8, 256, 0, stream>>>(
            cnts, slots, basis, att, msg);
        k_phaseB<<<(N_ENTITY + 3) / 4, 256, 0, stream>>>(
            cntd, novf, ovfd, msg, root, rgcn_bias, agg);
        k_attn<<<BATCH, 256, 0, stream>>>(seed_ids, agg, attn_a, attn_b, uT);
        k_scores<<<(N_ENTITY + 63) / 64, 256, 0, stream>>>(agg, uT, out_bias, out);
    } else {
        // fallback: dst counting-sort + fp32 gather
        float* agg   = (float*)d_ws;
        int*   hist  = (int*)(agg + AGG_F);     // NPAD
        int*   ptr   = hist + NPAD;
        int*   work  = ptr + NPAD;
        int*   part  = work + NPAD;             // 256
        int*   meta  = part + 256;              // N_EDGES
        float* uT    = (float*)(meta + N_EDGES);

        hipMemsetAsync(hist, 0, NPAD * sizeof(int), stream);
        k_histF<<<(N_EDGES + 255) / 256, 256, 0, stream>>>(edst, hist);
        k_scan1F<<<SCAN_NB, 256, 0, stream>>>(hist, ptr, part);
        k_scan23F<<<SCAN_NB, 256, 0, stream>>>(ptr, part, work);
        k_scatterF<<<(N_EDGES + 255) / 256, 256, 0, stream>>>(
            esrc, edst, etype, work, meta);
        k_gatherF<<<(N_ENTITY * 64 + 255) / 256, 256, 0, stream>>>(
            ptr, hist, meta, basis, att, root, rgcn_bias, agg);
        k_attn<<<BATCH, 256, 0, stream>>>(seed_ids, agg, attn_a, attn_b, uT);
        k_scores<<<(N_ENTITY + 63) / 64, 256, 0, stream>>>(agg, uT, out_bias, out);
    }
}